// Round 21
// baseline (268.691 us; speedup 1.0000x reference)
//
#include <hip/hip_runtime.h>
#include <math.h>

typedef _Float16 f16;
typedef f16 f16x8 __attribute__((ext_vector_type(8)));
typedef f16 f16x2 __attribute__((ext_vector_type(2)));
typedef float f32x4 __attribute__((ext_vector_type(4)));

// ---------------- problem constants ----------------
#define BB 2
#define QQ 2048
#define NOFF 36
#define NBQ (BB*QQ)          // 4096
#define NROWS (NOFF*NBQ)     // 147456  (row R = bq*36 + n)
#define NSE (NBQ*6)          // 24576 rows in SE/SO tables
#define FEAT_ELEMS (BB*66*66*64)
#define MROWS 48             // rows per workgroup
#define NWG (NROWS/MROWS)    // 3072
#define PITCHB 512           // bytes per sX row (256 halfs), chunks 0/1 + layers 1-3

// ---------------- kernel 1: conv 3x3, 3->64, padded NHWC, fp16 out ----------------
__global__ __launch_bounds__(256) void k_conv(const float* __restrict__ inp,
                                              const float* __restrict__ ew,
                                              const float* __restrict__ eb,
                                              f16* __restrict__ feat) {
    int idx = blockIdx.x * 256 + threadIdx.x;
    if (idx >= FEAT_ELEMS) return;
    int c = idx & 63;
    int t = idx >> 6;
    int x = t % 66; t /= 66;
    int y = t % 66;
    int b = t / 66;
    float v = 0.f;
    if (y >= 1 && y <= 64 && x >= 1 && x <= 64) {
        int yr = y - 1, xr = x - 1;
        v = eb[c];
        #pragma unroll
        for (int i = 0; i < 3; ++i)
            #pragma unroll
            for (int ky = 0; ky < 3; ++ky) {
                int yy = yr + ky - 1;
                if (yy < 0 || yy > 63) continue;
                #pragma unroll
                for (int kx = 0; kx < 3; ++kx) {
                    int xx = xr + kx - 1;
                    if (xx < 0 || xx > 63) continue;
                    v = fmaf(inp[((b*3 + i)*64 + yy)*64 + xx],
                             ew[((c*3 + i)*3 + ky)*3 + kx], v);
                }
            }
    }
    feat[idx] = (f16)v;
}

// ---------------- kernel 2: weight convert fp32 -> fp16, k-step-major ----------------
__global__ __launch_bounds__(256) void k_wcvt(const float* __restrict__ w0,
                                              const float* __restrict__ w1,
                                              const float* __restrict__ w2,
                                              const float* __restrict__ w3,
                                              const float* __restrict__ w4,
                                              f16* __restrict__ wt0, f16* __restrict__ wt1,
                                              f16* __restrict__ wt2, f16* __restrict__ wt3,
                                              f16* __restrict__ wt4,
                                              f16* __restrict__ w0x, f16* __restrict__ w0y) {
    int i = blockIdx.x * 256 + threadIdx.x;
    if (i < 19*256*32) {
        int kk = i & 31, col = (i >> 5) & 255, ks = i >> 13;
        int kp = ks*32 + kk;
        float v = 0.f;
        if (kp < 576) {
            int j = (kp & 63)*9 + (kp >> 6);   // s-major -> orig unfold index
            v = w0[j*256 + col];
        } else if (kp < 578) {
            v = w0[kp*256 + col];              // cell rows
        }
        wt0[i] = (f16)v;
        return;
    }
    i -= 19*256*32;
    if (i < 3*65536) {
        int l = i >> 16, j = i & 65535;
        int kk = j & 31, col = (j >> 5) & 255, ks = j >> 13;
        int k = ks*32 + kk;
        const float* w = (l == 0) ? w1 : (l == 1) ? w2 : w3;
        f16* wt = (l == 0) ? wt1 : (l == 1) ? wt2 : wt3;
        wt[j] = (f16)w[k*256 + col];
        return;
    }
    i -= 3*65536;
    if (i < 8192) {
        int kk = i & 31, col = (i >> 5) & 31, ks = i >> 10;
        int k = ks*32 + kk;
        wt4[i] = (f16)((col < 27) ? w4[k*27 + col] : 0.f);
        return;
    }
    i -= 8192;
    if (i < 2*9*256*32) {
        int half = i / (9*256*32);
        int j2 = i - half*(9*256*32);
        int kk = j2 & 31, col = (j2 >> 5) & 255, ks = j2 >> 13;
        int m = ks*32 + kk;                     // 0..287
        int j = (m >> 5)*64 + (m & 31) + (half ? 32 : 0);
        f16* dst = half ? w0y : w0x;
        dst[j2] = (f16)w0[j*256 + col];
    }
}

// ---------------- kernel 3: merged per-bq prep (area/ipos/wgt) ----------------
__global__ __launch_bounds__(256) void k_pw(const float* __restrict__ coord,
                                            float* __restrict__ wgtw,
                                            int* __restrict__ iposw) {
    int bq = blockIdx.x * 256 + threadIdx.x;
    if (bq >= NBQ) return;
    const float* cp = coord + bq * 18;
    const float offs[6] = {-3.f, -2.f, -1.f, 1.f, 2.f, 3.f};
    float rel0v[6], rel1v[6];
    int iyv[6], ixv[6];
    #pragma unroll
    for (int t = 0; t < 6; ++t) {
        float v = offs[t];
        float cc0 = cp[8] + v * (1.0f/64.0f) + 1e-6f;
        float cc1 = cp[9] + v * (1.0f/64.0f) + 1e-6f;
        cc0 = fminf(fmaxf(cc0, -1.f + 1e-6f), 1.f - 1e-6f);
        cc1 = fminf(fmaxf(cc1, -1.f + 1e-6f), 1.f - 1e-6f);
        int iy = (int)rintf(((cc0 + 1.f) * 64.f - 1.f) * 0.5f);
        int ix = (int)rintf(((cc1 + 1.f) * 64.f - 1.f) * 0.5f);
        iy = min(max(iy, 0), 63);
        ix = min(max(ix, 0), 63);
        float qc0 = -1.f + (2.f * (float)iy + 1.f) * (1.0f/64.0f);
        float qc1 = -1.f + (2.f * (float)ix + 1.f) * (1.0f/64.0f);
        rel0v[t] = (cp[0] - qc0) * 4096.f;
        rel1v[t] = (cp[1] - qc1);
        iyv[t] = iy; ixv[t] = ix;
    }
    int b = bq >> 11;
    float area[36];
    float tot = 0.f;
    #pragma unroll
    for (int n = 0; n < 36; ++n) {
        int i = n / 6, j = n - (n/6)*6;
        area[n] = fabsf(rel0v[i] * rel1v[j]) + 1e-9f;
        tot += area[n];
        iposw[bq*36 + n] = ((b*66 + iyv[i])*66 + ixv[j]) * 64;
    }
    #pragma unroll
    for (int n = 0; n < 36; ++n) {
        int pn = (n < 4) ? 3 - n : n;
        wgtw[bq*36 + n] = area[pn] / tot;
    }
}

// ---------------- generic direct-load GEMM (A from swizzled LDS) ----------------
template <int NKS, int NNT, int PITCHC>
__device__ __forceinline__ void gemmT(const f16* sA, const f16* __restrict__ Wt,
                                      int colbase, int lg,
                                      const uint (&abase)[3], uint aswz,
                                      f32x4 (&acc)[3][NNT]) {
    #pragma unroll
    for (int ks = 0; ks < NKS; ++ks) {
        f16x8 a[3], b[NNT];
        #pragma unroll
        for (int nt = 0; nt < NNT; ++nt)
            b[nt] = *(const f16x8*)(Wt + (ks*PITCHC + colbase + nt*16)*32 + lg*8);
        #pragma unroll
        for (int mt = 0; mt < 3; ++mt)
            a[mt] = *(const f16x8*)((const char*)sA + ((abase[mt] + (uint)(ks*64)) ^ aswz));
        __builtin_amdgcn_s_setprio(1);
        #pragma unroll
        for (int mt = 0; mt < 3; ++mt)
            #pragma unroll
            for (int nt = 0; nt < NNT; ++nt)
                acc[mt][nt] = __builtin_amdgcn_mfma_f32_16x16x32_f16(a[mt], b[nt], acc[mt][nt], 0, 0, 0);
        __builtin_amdgcn_s_setprio(0);
    }
}

// ---------------- kernel 4: SE/SO sinusoid GEMM (table type T) ----------------
template <typename T>
__global__ __launch_bounds__(256) void k_seso(const float* __restrict__ coord,
                                              const f16* __restrict__ w0x,
                                              const f16* __restrict__ w0y,
                                              T* __restrict__ se, T* __restrict__ so) {
    __shared__ f16 sS[48 * 320];          // 48 rows x 640 B (288 halfs + pad)
    __shared__ float s_cpx[48][9], s_cpy[48][9];
    __shared__ float s_div[16];

    int tid = threadIdx.x;
    int R0  = blockIdx.x * 48;

    if (tid < 16) s_div[tid] = expf((float)(2*tid) * -0.28782313662425575f);
    if (tid < 48) {
        int R = R0 + tid;
        int bq = R / 6, vi = R - bq*6;
        const float offs[6] = {-3.f, -2.f, -1.f, 1.f, 2.f, 3.f};
        float v = offs[vi];
        const float* cp = coord + bq * 18;
        float cc0 = cp[8] + v * (1.0f/64.0f) + 1e-6f;
        float cc1 = cp[9] + v * (1.0f/64.0f) + 1e-6f;
        cc0 = fminf(fmaxf(cc0, -1.f + 1e-6f), 1.f - 1e-6f);
        cc1 = fminf(fmaxf(cc1, -1.f + 1e-6f), 1.f - 1e-6f);
        int iy = (int)rintf(((cc0 + 1.f) * 64.f - 1.f) * 0.5f);
        int ix = (int)rintf(((cc1 + 1.f) * 64.f - 1.f) * 0.5f);
        iy = min(max(iy, 0), 63);
        ix = min(max(ix, 0), 63);
        float qc0 = -1.f + (2.f * (float)iy + 1.f) * (1.0f/64.0f);
        float qc1 = -1.f + (2.f * (float)ix + 1.f) * (1.0f/64.0f);
        #pragma unroll
        for (int pl = 0; pl < 9; ++pl) {
            s_cpx[tid][pl] = (cp[2*pl]     - qc0) * 4096.f;
            s_cpy[tid][pl] = (cp[2*pl + 1] - qc1);
        }
    }
    __syncthreads();

    int lane = tid & 63, wc = tid >> 6, l15 = lane & 15, lg = lane >> 4;
    uint aswz = (uint)((lane & 7) << 4);
    uint abase[3];
    #pragma unroll
    for (int mt = 0; mt < 3; ++mt)
        abase[mt] = (uint)((mt*16 + l15) * 640 + lg*16);
    int colbase = wc*64 + l15;

    #pragma unroll
    for (int half = 0; half < 2; ++half) {
        for (int idx = tid; idx < 48*288; idx += 256) {
            int r = idx / 288, m = idx - r*288;
            int pl = m >> 5, d = m & 31, t = d >> 1;
            float comp = half ? s_cpy[r][pl] : s_cpx[r][pl];
            float arg = comp * s_div[t];
            float rev = arg * 0.15915494309189535f;
            rev = rev - rintf(rev);
            float v = (d & 1) ? __builtin_amdgcn_cosf(rev) : __builtin_amdgcn_sinf(rev);
            uint off = (uint)(r*640 + m*2) ^ (uint)((r & 7) << 4);
            *(f16*)((char*)sS + off) = (f16)v;
        }
        __syncthreads();
        f32x4 acc[3][4];
        #pragma unroll
        for (int mt = 0; mt < 3; ++mt)
            #pragma unroll
            for (int nt = 0; nt < 4; ++nt)
                #pragma unroll
                for (int i = 0; i < 4; ++i) acc[mt][nt][i] = 0.f;
        gemmT<9,4,256>(sS, half ? w0y : w0x, colbase, lg, abase, aswz, acc);
        T* dst = half ? so : se;
        #pragma unroll
        for (int nt = 0; nt < 4; ++nt) {
            int col = wc*64 + nt*16 + l15;
            #pragma unroll
            for (int mt = 0; mt < 3; ++mt)
                #pragma unroll
                for (int i = 0; i < 4; ++i) {
                    int row = mt*16 + lg*4 + i;
                    dst[(size_t)(R0 + row)*256 + col] = (T)acc[mt][nt][i];
                }
        }
        __syncthreads();
    }
}

// ---------------- pipeline sync helpers ----------------
__device__ __forceinline__ void waitv4() {
    asm volatile("s_waitcnt vmcnt(4)" ::: "memory");
    __builtin_amdgcn_sched_barrier(0);
}
__device__ __forceinline__ void waitv0() {
    asm volatile("s_waitcnt vmcnt(0)" ::: "memory");
    __builtin_amdgcn_sched_barrier(0);
}
__device__ __forceinline__ void waitlgkm() {
    asm volatile("s_waitcnt lgkmcnt(0)" ::: "memory");
    __builtin_amdgcn_sched_barrier(0);
}
__device__ __forceinline__ void barrier() {
    __builtin_amdgcn_s_barrier();
    __builtin_amdgcn_sched_barrier(0);
}

// ---------------- kernel 5: fused MFMA MLP (table type T) ----------------
template <typename T>
__global__ __launch_bounds__(512, 4) void k_mlp(
    const float* __restrict__ cellp,
    const f16* __restrict__ feat,
    const float* __restrict__ wgtw, const int* __restrict__ iposw,
    const f16* __restrict__ wt0, const f16* __restrict__ wt1,
    const f16* __restrict__ wt2, const f16* __restrict__ wt3,
    const f16* __restrict__ wt4,
    const T* __restrict__ se, const T* __restrict__ so,
    const float* __restrict__ b0, const float* __restrict__ b1,
    const float* __restrict__ b2, const float* __restrict__ b3,
    const float* __restrict__ b4,
    float* __restrict__ partial)   // [NWG][2][28]
{
    __shared__ f16 sX[MROWS * 256];      // 24576 B activation / X-chunk buffer
    __shared__ f16 sBB[3][8192];         // 3 x 16 KB weight k-step tiles
    __shared__ float s_cx[MROWS], s_cy[MROWS], s_wgt[MROWS];
    __shared__ int   s_ipos[MROWS], s_sei[MROWS], s_soi[MROWS];

    int tid = threadIdx.x;
    int R0  = blockIdx.x * MROWS;

    if (tid < MROWS) {
        int R  = R0 + tid;
        int bq = R / 36, n = R - bq*36;
        s_wgt[tid]  = __builtin_nontemporal_load(&wgtw[R]);
        s_ipos[tid] = __builtin_nontemporal_load(&iposw[R]);
        s_cx[tid]   = cellp[bq*2 + 0] * 64.f;
        s_cy[tid]   = cellp[bq*2 + 1] * 64.f;
        s_sei[tid]  = (bq*6 + n/6) * 256;
        s_soi[tid]  = (bq*6 + n%6) * 256;
    }

    int lane = tid & 63;
    int wc   = tid >> 6;
    int l15  = lane & 15;
    int lg   = lane >> 4;
    uint aswz = (uint)((lane & 7) << 4);

    uint abase[3], abase2[3];
    #pragma unroll
    for (int mt = 0; mt < 3; ++mt) {
        int row = mt*16 + l15;
        abase[mt]  = (uint)(row * PITCHB + lg*16);
        abase2[mt] = (uint)(row * 256    + lg*16);   // chunk2 pitch
    }

    // bias preloads
    float bvL[4][2], bv4[2];
    {
        const float* Bs[4] = {b0, b1, b2, b3};
        #pragma unroll
        for (int L = 0; L < 4; ++L)
            #pragma unroll
            for (int nt = 0; nt < 2; ++nt) {
                bvL[L][nt] = Bs[L][wc*32 + nt*16 + l15];
                asm volatile("" :: "v"(bvL[L][nt]));
            }
        #pragma unroll
        for (int nt = 0; nt < 2; ++nt) {
            int col = nt*16 + l15;
            bv4[nt] = (col < 27) ? b4[col] : 0.f;
            asm volatile("" :: "v"(bv4[nt]));
        }
    }

    f32x4 acc[3][2];
    auto zacc = [&]() {
        #pragma unroll
        for (int mt = 0; mt < 3; ++mt)
            #pragma unroll
            for (int nt = 0; nt < 2; ++nt)
                #pragma unroll
                for (int i = 0; i < 4; ++i) acc[mt][nt][i] = 0.f;
    };

    // weight stage (waves 0-3, proven coalesced pattern)
    auto stageW = [&](f16* dst, const f16* __restrict__ Wt, int ks) {
        if (tid < 256) {
            const char* g = (const char*)Wt + (size_t)ks * 16384 + (size_t)tid * 64;
            char* d = (char*)dst + tid * 16;
            #pragma unroll
            for (int i = 0; i < 4; ++i) {
                __builtin_amdgcn_global_load_lds(
                    (const __attribute__((address_space(1))) void*)(g + i*16),
                    (__attribute__((address_space(3))) void*)(d + i*4096),
                    16, 0, 0);
            }
        }
        __builtin_amdgcn_sched_barrier(0);
    };

    // X chunk stage (phases 0/1: s = phase*4 .. +3), pre-swizzled global sources.
    auto stageXc = [&](int phase) {
        #pragma unroll
        for (int i = 0; i < 3; ++i) {
            int chunk = tid + i*512;          // 0..1535, 16B each
            int r = chunk >> 5;
            int w = (chunk & 31) << 4;
            int wl = w ^ ((r & 7) << 4);      // logical byte in row
            int jp = wl >> 1;                 // 0..255
            int s = phase*4 + (jp >> 6);
            int c = jp & 63;
            int doff = (s/3)*66 + (s - (s/3)*3);
            const f16* src = feat + (s_ipos[r] + doff*64 + c);
            __builtin_amdgcn_global_load_lds(
                (const __attribute__((address_space(1))) void*)src,
                (__attribute__((address_space(3))) void*)((char*)sX + chunk*16),
                16, 0, 0);
        }
        __builtin_amdgcn_sched_barrier(0);
    };

    // X chunk 2: 48 rows x 256B (s=8 feat in [0,128), cell region [128,192), pad).
    auto stageXc2 = [&]() {
        #pragma unroll
        for (int i = 0; i < 2; ++i) {
            int chunk = tid + i*512;
            if (chunk < 768) {
                int r = chunk >> 4;
                int w = (chunk & 15) << 4;
                const f16* src;
                int ip = s_ipos[r];
                if (w < 128) {
                    int wl = w ^ ((r & 7) << 4);
                    src = feat + (ip + 134*64 + (wl >> 1));   // s=8: doff = 2*66+2
                } else {
                    src = feat + ip;                           // dummy, overwritten
                }
                __builtin_amdgcn_global_load_lds(
                    (const __attribute__((address_space(1))) void*)src,
                    (__attribute__((address_space(3))) void*)((char*)sX + chunk*16),
                    16, 0, 0);
            }
        }
        __builtin_amdgcn_sched_barrier(0);
    };

    auto computeK = [&](const f16* sB, int lks) {
        f16x8 a[3], b[2];
        #pragma unroll
        for (int nt = 0; nt < 2; ++nt)
            b[nt] = *(const f16x8*)((const char*)sB + lg*4096 + (wc*32 + nt*16 + l15)*16);
        #pragma unroll
        for (int mt = 0; mt < 3; ++mt)
            a[mt] = *(const f16x8*)((const char*)sX + ((abase[mt] + (uint)(lks*64)) ^ aswz));
        __builtin_amdgcn_s_setprio(1);
        #pragma unroll
        for (int mt = 0; mt < 3; ++mt)
            #pragma unroll
            for (int nt = 0; nt < 2; ++nt)
                acc[mt][nt] = __builtin_amdgcn_mfma_f32_16x16x32_f16(a[mt], b[nt], acc[mt][nt], 0, 0, 0);
        __builtin_amdgcn_s_setprio(0);
    };
    auto computeK2 = [&](const f16* sB, int lks) {   // chunk2 (pitch 256)
        f16x8 a[3], b[2];
        #pragma unroll
        for (int nt = 0; nt < 2; ++nt)
            b[nt] = *(const f16x8*)((const char*)sB + lg*4096 + (wc*32 + nt*16 + l15)*16);
        #pragma unroll
        for (int mt = 0; mt < 3; ++mt)
            a[mt] = *(const f16x8*)((const char*)sX + ((abase2[mt] + (uint)(lks*64)) ^ aswz));
        __builtin_amdgcn_s_setprio(1);
        #pragma unroll
        for (int mt = 0; mt < 3; ++mt)
            #pragma unroll
            for (int nt = 0; nt < 2; ++nt)
                acc[mt][nt] = __builtin_amdgcn_mfma_f32_16x16x32_f16(a[mt], b[nt], acc[mt][nt], 0, 0, 0);
        __builtin_amdgcn_s_setprio(0);
    };

    auto epi = [&](const float (&bv)[2]) {
        #pragma unroll
        for (int nt = 0; nt < 2; ++nt) {
            int col = wc*32 + nt*16 + l15;
            #pragma unroll
            for (int mt = 0; mt < 3; ++mt)
                #pragma unroll
                for (int i = 0; i < 4; ++i) {
                    int row = mt*16 + lg*4 + i;
                    float v = fmaxf(acc[mt][nt][i] + bv[nt], 0.f);
                    uint off = (uint)(row*PITCHB + col*2) ^ (uint)((row & 7) << 4);
                    *(f16*)((char*)sX + off) = (f16)v;
                }
        }
    };
    // L0 epilogue: += SE/SO, bias, relu
    auto epi0 = [&](const float (&bv)[2]) {
        #pragma unroll
        for (int mt = 0; mt < 3; ++mt)
            #pragma unroll
            for (int i = 0; i < 4; ++i) {
                int row = mt*16 + lg*4 + i;
                int sei = s_sei[row], soi = s_soi[row];
                #pragma unroll
                for (int nt = 0; nt < 2; ++nt) {
                    int col = wc*32 + nt*16 + l15;
                    float addv = (float)se[sei + col] + (float)so[soi + col];
                    float v = fmaxf(acc[mt][nt][i] + addv + bv[nt], 0.f);
                    uint off = (uint)(row*PITCHB + col*2) ^ (uint)((row & 7) << 4);
                    *(f16*)((char*)sX + off) = (f16)v;
                }
            }
    };

    __syncthreads();   // header visible

    // ================= layer 0 : 19 ksteps, X in 3 staged chunks =================
    zacc();
    stageXc(0);
    stageW(sBB[0], wt0, 0);
    stageW(sBB[1], wt0, 1);
    waitv0(); barrier();                        // RACE FIX: drain ALL waves' X loads
                                                // (waves 4-7 have only 3 outstanding;
                                                //  vmcnt(4) was a no-op for them)
    #pragma unroll
    for (int ks = 0; ks < 7; ++ks) {
        stageW(sBB[(ks + 2) % 3], wt0, ks + 2);
        computeK(sBB[ks % 3], ks);
        waitv4(); barrier();
    }
    stageW(sBB[0], wt0, 9);                     // ks7
    computeK(sBB[1], 7);
    waitv4(); barrier();                        // all chunk0 reads done
    stageXc(1);
    waitv0(); barrier();                        // X1 (+W8,W9) landed; re-prime
    #pragma unroll
    for (int ks = 8; ks < 15; ++ks) {
        stageW(sBB[(ks + 2) % 3], wt0, ks + 2);
        computeK(sBB[ks % 3], ks - 8);
        waitv4(); barrier();
    }
    stageW(sBB[2], wt0, 17);                    // ks15
    computeK(sBB[0], 7);
    waitv4(); barrier();                        // all chunk1 reads done
    stageXc2();
    waitv0();                                   // X2 (+W16,W17) landed
    if (tid < 48) {                             // cell + zero fill over dummy region
        uint base = (uint)(tid * 256);
        uint sw   = (uint)((tid & 7) << 4);
        f16x2 cv = { (f16)s_cx[tid], (f16)s_cy[tid] };
        *(f16x2*)((char*)sX + base + (128u ^ sw)) = cv;
        f16x2 z = { (f16)0.f, (f16)0.f };
        #pragma unroll
        for (int q = 66; q < 96; q += 2)
            *(f16x2*)((char*)sX + base + (((uint)(q*2)) ^ sw)) = z;
    }
    waitlgkm(); barrier();
    stageW(sBB[0], wt0, 18);
    computeK2(sBB[1], 0);                       // ks16
    computeK2(sBB[2], 1);                       // ks17
    waitv0();
    computeK2(sBB[0], 2);                       // ks18
    barrier();                                  // all L0 reads done

    // ================= layers 1..3 =================
    const f16* Ws[3] = {wt1, wt2, wt3};
    #pragma unroll
    for (int L = 0; L < 3; ++L) {
        stageW(sBB[0], Ws[L], 0);
        stageW(sBB[1], Ws[L], 1);
        if (L == 0) epi0(bvL[0]); else epi(bvL[L]);
        zacc();
        waitv4(); waitlgkm(); barrier();
        #pragma unroll
        for (int ks = 0; ks < 6; ++ks) {
            stageW(sBB[(ks + 2) % 3], Ws[L], ks + 2);
            computeK(sBB[ks % 3], ks);
            waitv4(); barrier();
        }
        computeK(sBB[0], 6);
        waitv0(); barrier();
        computeK(sBB[1], 7);
        barrier();
    }
    epi(bvL[3]);
    waitlgkm(); barrier();

    // ---- layer 4 : 256 -> 27 (padded 32), wave 0 only, + weighted segment sums ----
    if (wc == 0) {
        f32x4 a4[3][2];
        #pragma unroll
        for (int mt = 0; mt < 3; ++mt)
            #pragma unroll
            for (int nt = 0; nt < 2; ++nt)
                #pragma unroll
                for (int i = 0; i < 4; ++i) a4[mt][nt][i] = 0.f;
        gemmT<8,2,32>(sX, wt4, l15, lg, abase, aswz, a4);
        int split = 36 - (R0 % 36);
        #pragma unroll
        for (int nt = 0; nt < 2; ++nt) {
            int col = nt*16 + l15;
            float s0 = 0.f, s1 = 0.f;
            #pragma unroll
            for (int mt = 0; mt < 3; ++mt)
                #pragma unroll
                for (int i = 0; i < 4; ++i) {
                    int row = mt*16 + lg*4 + i;
                    float v = (a4[mt][nt][i] + bv4[nt]) * s_wgt[row];
                    if (row < split) s0 += v; else s1 += v;
                }
            s0 += __shfl_xor(s0, 16, 64);
            s0 += __shfl_xor(s0, 32, 64);
            s1 += __shfl_xor(s1, 16, 64);
            s1 += __shfl_xor(s1, 32, 64);
            if (lg == 0 && col < 27) {
                __builtin_nontemporal_store(s0, &partial[(size_t)blockIdx.x*56 + col]);
                __builtin_nontemporal_store(s1, &partial[(size_t)blockIdx.x*56 + 28 + col]);
            }
        }
    }
}

// ---------------- kernel 6: combine <=2 window partials per bq ----------------
__global__ __launch_bounds__(256) void k_red(const float* __restrict__ partial,
                                             float* __restrict__ out) {
    int i = blockIdx.x * 256 + threadIdx.x;
    if (i >= NBQ * 27) return;
    int bq = i / 27, col = i - bq*27;
    int r_lo = bq * 36;
    int w0 = r_lo / 48, w1 = (r_lo + 35) / 48;
    float s = 0.f;
    for (int w = w0; w <= w1; ++w) {
        int seg = (bq == (w*48)/36) ? 0 : 1;
        s += __builtin_nontemporal_load(&partial[(size_t)w*56 + seg*28 + col]);
    }
    out[i] = s;
}

// ---------------- launch ----------------
extern "C" void kernel_launch(void* const* d_in, const int* in_sizes, int n_in,
                              void* d_out, int out_size, void* d_ws, size_t ws_size,
                              hipStream_t stream) {
    const float* inp   = (const float*)d_in[0];
    const float* coord = (const float*)d_in[1];
    const float* cellp = (const float*)d_in[2];
    const float* enc_w = (const float*)d_in[3];
    const float* enc_b = (const float*)d_in[4];
    const float* w0 = (const float*)d_in[5];
    const float* b0 = (const float*)d_in[6];
    const float* w1 = (const float*)d_in[7];
    const float* b1 = (const float*)d_in[8];
    const float* w2 = (const float*)d_in[9];
    const float* b2 = (const float*)d_in[10];
    const float* w3 = (const float*)d_in[11];
    const float* b3 = (const float*)d_in[12];
    const float* w4 = (const float*)d_in[13];
    const float* b4 = (const float*)d_in[14];
    float* outp = (float*)d_out;

    float* ws    = (float*)d_ws;
    f16*   feat  = (f16*)ws;                          // FEAT_ELEMS halfs
    float* wgtw  = (float*)(feat + FEAT_ELEMS);       // NROWS
    int*   iposw = (int*)(wgtw + NROWS);
    float* partial = (float*)(iposw + NROWS);         // NWG*56
    f16*   wt0   = (f16*)(partial + (size_t)NWG*56);  // 19*256*32
    f16*   wt1   = wt0 + 19*256*32;
    f16*   wt2   = wt1 + 65536;
    f16*   wt3   = wt2 + 65536;
    f16*   wt4   = wt3 + 65536;                       // 8192
    f16*   w0x   = wt4 + 8192;                        // 9*256*32
    f16*   w0y   = w0x + 9*256*32;
    char*  tbl   = (char*)(w0y + 9*256*32);           // table region start

    size_t fixedBytes = (size_t)(tbl - (char*)d_ws);
    size_t f32Bytes   = (size_t)2 * NSE * 256 * sizeof(float);
    bool   useF32     = (fixedBytes + f32Bytes) <= ws_size;

    k_conv<<<(FEAT_ELEMS + 255)/256, 256, 0, stream>>>(inp, enc_w, enc_b, feat);
    k_wcvt<<<1984, 256, 0, stream>>>(w0, w1, w2, w3, w4, wt0, wt1, wt2, wt3, wt4, w0x, w0y);
    k_pw<<<(NBQ + 255)/256, 256, 0, stream>>>(coord, wgtw, iposw);

    if (useF32) {
        float* sep = (float*)tbl;
        float* sop = sep + (size_t)NSE*256;
        k_seso<float><<<NSE/48, 256, 0, stream>>>(coord, w0x, w0y, sep, sop);
        k_mlp<float><<<NWG, 512, 0, stream>>>(cellp, feat, wgtw, iposw,
                                              wt0, wt1, wt2, wt3, wt4, sep, sop,
                                              b0, b1, b2, b3, b4, partial);
    } else {
        f16* sep = (f16*)tbl;
        f16* sop = sep + (size_t)NSE*256;
        k_seso<f16><<<NSE/48, 256, 0, stream>>>(coord, w0x, w0y, sep, sop);
        k_mlp<f16><<<NWG, 512, 0, stream>>>(cellp, feat, wgtw, iposw,
                                            wt0, wt1, wt2, wt3, wt4, sep, sop,
                                            b0, b1, b2, b3, b4, partial);
    }
    k_red<<<(NBQ*27 + 255)/256, 256, 0, stream>>>(partial, outp);
}

// Round 22
// 262.201 us; speedup vs baseline: 1.0248x; 1.0248x over previous
//
#include <hip/hip_runtime.h>
#include <math.h>

typedef _Float16 f16;
typedef f16 f16x8 __attribute__((ext_vector_type(8)));
typedef f16 f16x2 __attribute__((ext_vector_type(2)));
typedef float f32x4 __attribute__((ext_vector_type(4)));

// ---------------- problem constants ----------------
#define BB 2
#define QQ 2048
#define NOFF 36
#define NBQ (BB*QQ)          // 4096
#define NROWS (NOFF*NBQ)     // 147456  (row R = bq*36 + n)
#define NSE (NBQ*6)          // 24576 rows in SE/SO tables
#define FEAT_ELEMS (BB*66*66*64)   // 557568
#define MROWS 48             // rows per workgroup
#define NWG (NROWS/MROWS)    // 3072
#define PITCHB 512           // bytes per sX row (256 halfs)

#define NB_CONV (FEAT_ELEMS/256)   // 2178
#define NB_WCVT 1984
#define NB_PW   ((NBQ+255)/256)    // 16

// ---------------- kernel 1: merged prologue (conv | wcvt | pw by block range) ----------------
__global__ __launch_bounds__(256) void k_pre(
    const float* __restrict__ inp, const float* __restrict__ ew, const float* __restrict__ eb,
    f16* __restrict__ feat,
    const float* __restrict__ w0, const float* __restrict__ w1, const float* __restrict__ w2,
    const float* __restrict__ w3, const float* __restrict__ w4,
    f16* __restrict__ wt0, f16* __restrict__ wt1, f16* __restrict__ wt2,
    f16* __restrict__ wt3, f16* __restrict__ wt4,
    f16* __restrict__ w0x, f16* __restrict__ w0y,
    const float* __restrict__ coord, float* __restrict__ wgtw, int* __restrict__ iposw)
{
    int blk = blockIdx.x;
    int tid = threadIdx.x;
    if (blk < NB_CONV) {
        // ---- conv 3x3, 3->64, padded NHWC, fp16 out ----
        int idx = blk * 256 + tid;
        int c = idx & 63;
        int t = idx >> 6;
        int x = t % 66; t /= 66;
        int y = t % 66;
        int b = t / 66;
        float v = 0.f;
        if (y >= 1 && y <= 64 && x >= 1 && x <= 64) {
            int yr = y - 1, xr = x - 1;
            v = eb[c];
            #pragma unroll
            for (int i = 0; i < 3; ++i)
                #pragma unroll
                for (int ky = 0; ky < 3; ++ky) {
                    int yy = yr + ky - 1;
                    if (yy < 0 || yy > 63) continue;
                    #pragma unroll
                    for (int kx = 0; kx < 3; ++kx) {
                        int xx = xr + kx - 1;
                        if (xx < 0 || xx > 63) continue;
                        v = fmaf(inp[((b*3 + i)*64 + yy)*64 + xx],
                                 ew[((c*3 + i)*3 + ky)*3 + kx], v);
                    }
                }
        }
        feat[idx] = (f16)v;
        return;
    }
    if (blk < NB_CONV + NB_WCVT) {
        // ---- weight convert fp32 -> fp16, k-step-major ----
        int i = (blk - NB_CONV) * 256 + tid;
        if (i < 19*256*32) {
            int kk = i & 31, col = (i >> 5) & 255, ks = i >> 13;
            int kp = ks*32 + kk;
            float v = 0.f;
            if (kp < 576) {
                int j = (kp & 63)*9 + (kp >> 6);   // s-major -> orig unfold index
                v = w0[j*256 + col];
            } else if (kp < 578) {
                v = w0[kp*256 + col];              // cell rows
            }
            wt0[i] = (f16)v;
            return;
        }
        i -= 19*256*32;
        if (i < 3*65536) {
            int l = i >> 16, j = i & 65535;
            int kk = j & 31, col = (j >> 5) & 255, ks = j >> 13;
            int k = ks*32 + kk;
            const float* w = (l == 0) ? w1 : (l == 1) ? w2 : w3;
            f16* wt = (l == 0) ? wt1 : (l == 1) ? wt2 : wt3;
            wt[j] = (f16)w[k*256 + col];
            return;
        }
        i -= 3*65536;
        if (i < 8192) {
            int kk = i & 31, col = (i >> 5) & 31, ks = i >> 10;
            int k = ks*32 + kk;
            wt4[i] = (f16)((col < 27) ? w4[k*27 + col] : 0.f);
            return;
        }
        i -= 8192;
        if (i < 2*9*256*32) {
            int half = i / (9*256*32);
            int j2 = i - half*(9*256*32);
            int kk = j2 & 31, col = (j2 >> 5) & 255, ks = j2 >> 13;
            int m = ks*32 + kk;                     // 0..287
            int j = (m >> 5)*64 + (m & 31) + (half ? 32 : 0);
            f16* dst = half ? w0y : w0x;
            dst[j2] = (f16)w0[j*256 + col];
        }
        return;
    }
    // ---- per-bq prep (area/ipos/wgt) ----
    int bq = (blk - NB_CONV - NB_WCVT) * 256 + tid;
    if (bq >= NBQ) return;
    const float* cp = coord + bq * 18;
    const float offs[6] = {-3.f, -2.f, -1.f, 1.f, 2.f, 3.f};
    float rel0v[6], rel1v[6];
    int iyv[6], ixv[6];
    #pragma unroll
    for (int t = 0; t < 6; ++t) {
        float v = offs[t];
        float cc0 = cp[8] + v * (1.0f/64.0f) + 1e-6f;
        float cc1 = cp[9] + v * (1.0f/64.0f) + 1e-6f;
        cc0 = fminf(fmaxf(cc0, -1.f + 1e-6f), 1.f - 1e-6f);
        cc1 = fminf(fmaxf(cc1, -1.f + 1e-6f), 1.f - 1e-6f);
        int iy = (int)rintf(((cc0 + 1.f) * 64.f - 1.f) * 0.5f);
        int ix = (int)rintf(((cc1 + 1.f) * 64.f - 1.f) * 0.5f);
        iy = min(max(iy, 0), 63);
        ix = min(max(ix, 0), 63);
        float qc0 = -1.f + (2.f * (float)iy + 1.f) * (1.0f/64.0f);
        float qc1 = -1.f + (2.f * (float)ix + 1.f) * (1.0f/64.0f);
        rel0v[t] = (cp[0] - qc0) * 4096.f;
        rel1v[t] = (cp[1] - qc1);
        iyv[t] = iy; ixv[t] = ix;
    }
    int b = bq >> 11;
    float area[36];
    float tot = 0.f;
    #pragma unroll
    for (int n = 0; n < 36; ++n) {
        int i = n / 6, j = n - (n/6)*6;
        area[n] = fabsf(rel0v[i] * rel1v[j]) + 1e-9f;
        tot += area[n];
        iposw[bq*36 + n] = ((b*66 + iyv[i])*66 + ixv[j]) * 64;
    }
    #pragma unroll
    for (int n = 0; n < 36; ++n) {
        int pn = (n < 4) ? 3 - n : n;
        wgtw[bq*36 + n] = area[pn] / tot;
    }
}

// ---------------- generic direct-load GEMM (A from swizzled LDS) ----------------
template <int NKS, int NNT, int PITCHC>
__device__ __forceinline__ void gemmT(const f16* sA, const f16* __restrict__ Wt,
                                      int colbase, int lg,
                                      const uint (&abase)[3], uint aswz,
                                      f32x4 (&acc)[3][NNT]) {
    #pragma unroll
    for (int ks = 0; ks < NKS; ++ks) {
        f16x8 a[3], b[NNT];
        #pragma unroll
        for (int nt = 0; nt < NNT; ++nt)
            b[nt] = *(const f16x8*)(Wt + (ks*PITCHC + colbase + nt*16)*32 + lg*8);
        #pragma unroll
        for (int mt = 0; mt < 3; ++mt)
            a[mt] = *(const f16x8*)((const char*)sA + ((abase[mt] + (uint)(ks*64)) ^ aswz));
        __builtin_amdgcn_s_setprio(1);
        #pragma unroll
        for (int mt = 0; mt < 3; ++mt)
            #pragma unroll
            for (int nt = 0; nt < NNT; ++nt)
                acc[mt][nt] = __builtin_amdgcn_mfma_f32_16x16x32_f16(a[mt], b[nt], acc[mt][nt], 0, 0, 0);
        __builtin_amdgcn_s_setprio(0);
    }
}

// ---------------- kernel 2: SE/SO sinusoid GEMM (table type T) ----------------
template <typename T>
__global__ __launch_bounds__(256) void k_seso(const float* __restrict__ coord,
                                              const f16* __restrict__ w0x,
                                              const f16* __restrict__ w0y,
                                              T* __restrict__ se, T* __restrict__ so) {
    __shared__ f16 sS[48 * 320];          // 48 rows x 640 B (288 halfs + pad)
    __shared__ float s_cpx[48][9], s_cpy[48][9];
    __shared__ float s_div[16];

    int tid = threadIdx.x;
    int R0  = blockIdx.x * 48;

    if (tid < 16) s_div[tid] = expf((float)(2*tid) * -0.28782313662425575f);
    if (tid < 48) {
        int R = R0 + tid;
        int bq = R / 6, vi = R - bq*6;
        const float offs[6] = {-3.f, -2.f, -1.f, 1.f, 2.f, 3.f};
        float v = offs[vi];
        const float* cp = coord + bq * 18;
        float cc0 = cp[8] + v * (1.0f/64.0f) + 1e-6f;
        float cc1 = cp[9] + v * (1.0f/64.0f) + 1e-6f;
        cc0 = fminf(fmaxf(cc0, -1.f + 1e-6f), 1.f - 1e-6f);
        cc1 = fminf(fmaxf(cc1, -1.f + 1e-6f), 1.f - 1e-6f);
        int iy = (int)rintf(((cc0 + 1.f) * 64.f - 1.f) * 0.5f);
        int ix = (int)rintf(((cc1 + 1.f) * 64.f - 1.f) * 0.5f);
        iy = min(max(iy, 0), 63);
        ix = min(max(ix, 0), 63);
        float qc0 = -1.f + (2.f * (float)iy + 1.f) * (1.0f/64.0f);
        float qc1 = -1.f + (2.f * (float)ix + 1.f) * (1.0f/64.0f);
        #pragma unroll
        for (int pl = 0; pl < 9; ++pl) {
            s_cpx[tid][pl] = (cp[2*pl]     - qc0) * 4096.f;
            s_cpy[tid][pl] = (cp[2*pl + 1] - qc1);
        }
    }
    __syncthreads();

    int lane = tid & 63, wc = tid >> 6, l15 = lane & 15, lg = lane >> 4;
    uint aswz = (uint)((lane & 7) << 4);
    uint abase[3];
    #pragma unroll
    for (int mt = 0; mt < 3; ++mt)
        abase[mt] = (uint)((mt*16 + l15) * 640 + lg*16);
    int colbase = wc*64 + l15;

    #pragma unroll
    for (int half = 0; half < 2; ++half) {
        for (int idx = tid; idx < 48*288; idx += 256) {
            int r = idx / 288, m = idx - r*288;
            int pl = m >> 5, d = m & 31, t = d >> 1;
            float comp = half ? s_cpy[r][pl] : s_cpx[r][pl];
            float arg = comp * s_div[t];
            float rev = arg * 0.15915494309189535f;
            rev = rev - rintf(rev);
            float v = (d & 1) ? __builtin_amdgcn_cosf(rev) : __builtin_amdgcn_sinf(rev);
            uint off = (uint)(r*640 + m*2) ^ (uint)((r & 7) << 4);
            *(f16*)((char*)sS + off) = (f16)v;
        }
        __syncthreads();
        f32x4 acc[3][4];
        #pragma unroll
        for (int mt = 0; mt < 3; ++mt)
            #pragma unroll
            for (int nt = 0; nt < 4; ++nt)
                #pragma unroll
                for (int i = 0; i < 4; ++i) acc[mt][nt][i] = 0.f;
        gemmT<9,4,256>(sS, half ? w0y : w0x, colbase, lg, abase, aswz, acc);
        T* dst = half ? so : se;
        #pragma unroll
        for (int nt = 0; nt < 4; ++nt) {
            int col = wc*64 + nt*16 + l15;
            #pragma unroll
            for (int mt = 0; mt < 3; ++mt)
                #pragma unroll
                for (int i = 0; i < 4; ++i) {
                    int row = mt*16 + lg*4 + i;
                    dst[(size_t)(R0 + row)*256 + col] = (T)acc[mt][nt][i];
                }
        }
        __syncthreads();
    }
}

// ---------------- pipeline sync helpers ----------------
__device__ __forceinline__ void waitv4() {
    asm volatile("s_waitcnt vmcnt(4)" ::: "memory");
    __builtin_amdgcn_sched_barrier(0);
}
__device__ __forceinline__ void waitv0() {
    asm volatile("s_waitcnt vmcnt(0)" ::: "memory");
    __builtin_amdgcn_sched_barrier(0);
}
__device__ __forceinline__ void waitlgkm() {
    asm volatile("s_waitcnt lgkmcnt(0)" ::: "memory");
    __builtin_amdgcn_sched_barrier(0);
}
__device__ __forceinline__ void barrier() {
    __builtin_amdgcn_s_barrier();
    __builtin_amdgcn_sched_barrier(0);
}

// ---------------- kernel 3: fused MFMA MLP (table type T) ----------------
template <typename T>
__global__ __launch_bounds__(512, 4) void k_mlp(
    const float* __restrict__ cellp,
    const f16* __restrict__ feat,
    const float* __restrict__ wgtw, const int* __restrict__ iposw,
    const f16* __restrict__ wt0, const f16* __restrict__ wt1,
    const f16* __restrict__ wt2, const f16* __restrict__ wt3,
    const f16* __restrict__ wt4,
    const T* __restrict__ se, const T* __restrict__ so,
    const float* __restrict__ b0, const float* __restrict__ b1,
    const float* __restrict__ b2, const float* __restrict__ b3,
    const float* __restrict__ b4,
    float* __restrict__ partial)   // [NWG][2][28]
{
    __shared__ f16 sX[MROWS * 256];      // 24576 B activation / X-chunk buffer
    __shared__ f16 sBB[3][8192];         // 3 x 16 KB weight k-step tiles
    __shared__ float s_cx[MROWS], s_cy[MROWS], s_wgt[MROWS];
    __shared__ int   s_ipos[MROWS], s_sei[MROWS], s_soi[MROWS];

    int tid = threadIdx.x;
    int R0  = blockIdx.x * MROWS;

    if (tid < MROWS) {
        int R  = R0 + tid;
        int bq = R / 36, n = R - bq*36;
        s_wgt[tid]  = __builtin_nontemporal_load(&wgtw[R]);
        s_ipos[tid] = __builtin_nontemporal_load(&iposw[R]);
        s_cx[tid]   = cellp[bq*2 + 0] * 64.f;
        s_cy[tid]   = cellp[bq*2 + 1] * 64.f;
        s_sei[tid]  = (bq*6 + n/6) * 256;
        s_soi[tid]  = (bq*6 + n%6) * 256;
    }

    int lane = tid & 63;
    int wc   = tid >> 6;
    int l15  = lane & 15;
    int lg   = lane >> 4;
    uint aswz = (uint)((lane & 7) << 4);

    uint abase[3], abase2[3];
    #pragma unroll
    for (int mt = 0; mt < 3; ++mt) {
        int row = mt*16 + l15;
        abase[mt]  = (uint)(row * PITCHB + lg*16);
        abase2[mt] = (uint)(row * 256    + lg*16);   // chunk2 pitch
    }

    // bias preloads
    float bvL[4][2], bv4[2];
    {
        const float* Bs[4] = {b0, b1, b2, b3};
        #pragma unroll
        for (int L = 0; L < 4; ++L)
            #pragma unroll
            for (int nt = 0; nt < 2; ++nt) {
                bvL[L][nt] = Bs[L][wc*32 + nt*16 + l15];
                asm volatile("" :: "v"(bvL[L][nt]));
            }
        #pragma unroll
        for (int nt = 0; nt < 2; ++nt) {
            int col = nt*16 + l15;
            bv4[nt] = (col < 27) ? b4[col] : 0.f;
            asm volatile("" :: "v"(bv4[nt]));
        }
    }

    f32x4 acc[3][2];
    auto zacc = [&]() {
        #pragma unroll
        for (int mt = 0; mt < 3; ++mt)
            #pragma unroll
            for (int nt = 0; nt < 2; ++nt)
                #pragma unroll
                for (int i = 0; i < 4; ++i) acc[mt][nt][i] = 0.f;
    };

    // weight stage (waves 0-3, proven coalesced pattern)
    auto stageW = [&](f16* dst, const f16* __restrict__ Wt, int ks) {
        if (tid < 256) {
            const char* g = (const char*)Wt + (size_t)ks * 16384 + (size_t)tid * 64;
            char* d = (char*)dst + tid * 16;
            #pragma unroll
            for (int i = 0; i < 4; ++i) {
                __builtin_amdgcn_global_load_lds(
                    (const __attribute__((address_space(1))) void*)(g + i*16),
                    (__attribute__((address_space(3))) void*)(d + i*4096),
                    16, 0, 0);
            }
        }
        __builtin_amdgcn_sched_barrier(0);
    };

    // X chunk stage (phases 0/1: s = phase*4 .. +3), pre-swizzled global sources.
    auto stageXc = [&](int phase) {
        #pragma unroll
        for (int i = 0; i < 3; ++i) {
            int chunk = tid + i*512;          // 0..1535, 16B each
            int r = chunk >> 5;
            int w = (chunk & 31) << 4;
            int wl = w ^ ((r & 7) << 4);      // logical byte in row
            int jp = wl >> 1;                 // 0..255
            int s = phase*4 + (jp >> 6);
            int c = jp & 63;
            int doff = (s/3)*66 + (s - (s/3)*3);
            const f16* src = feat + (s_ipos[r] + doff*64 + c);
            __builtin_amdgcn_global_load_lds(
                (const __attribute__((address_space(1))) void*)src,
                (__attribute__((address_space(3))) void*)((char*)sX + chunk*16),
                16, 0, 0);
        }
        __builtin_amdgcn_sched_barrier(0);
    };

    // X chunk 2: 48 rows x 256B (s=8 feat in [0,128), cell region [128,192), pad).
    auto stageXc2 = [&]() {
        #pragma unroll
        for (int i = 0; i < 2; ++i) {
            int chunk = tid + i*512;
            if (chunk < 768) {
                int r = chunk >> 4;
                int w = (chunk & 15) << 4;
                const f16* src;
                int ip = s_ipos[r];
                if (w < 128) {
                    int wl = w ^ ((r & 7) << 4);
                    src = feat + (ip + 134*64 + (wl >> 1));   // s=8: doff = 2*66+2
                } else {
                    src = feat + ip;                           // dummy, overwritten
                }
                __builtin_amdgcn_global_load_lds(
                    (const __attribute__((address_space(1))) void*)src,
                    (__attribute__((address_space(3))) void*)((char*)sX + chunk*16),
                    16, 0, 0);
            }
        }
        __builtin_amdgcn_sched_barrier(0);
    };

    auto computeK = [&](const f16* sB, int lks) {
        f16x8 a[3], b[2];
        #pragma unroll
        for (int nt = 0; nt < 2; ++nt)
            b[nt] = *(const f16x8*)((const char*)sB + lg*4096 + (wc*32 + nt*16 + l15)*16);
        #pragma unroll
        for (int mt = 0; mt < 3; ++mt)
            a[mt] = *(const f16x8*)((const char*)sX + ((abase[mt] + (uint)(lks*64)) ^ aswz));
        __builtin_amdgcn_s_setprio(1);
        #pragma unroll
        for (int mt = 0; mt < 3; ++mt)
            #pragma unroll
            for (int nt = 0; nt < 2; ++nt)
                acc[mt][nt] = __builtin_amdgcn_mfma_f32_16x16x32_f16(a[mt], b[nt], acc[mt][nt], 0, 0, 0);
        __builtin_amdgcn_s_setprio(0);
    };
    auto computeK2 = [&](const f16* sB, int lks) {   // chunk2 (pitch 256)
        f16x8 a[3], b[2];
        #pragma unroll
        for (int nt = 0; nt < 2; ++nt)
            b[nt] = *(const f16x8*)((const char*)sB + lg*4096 + (wc*32 + nt*16 + l15)*16);
        #pragma unroll
        for (int mt = 0; mt < 3; ++mt)
            a[mt] = *(const f16x8*)((const char*)sX + ((abase2[mt] + (uint)(lks*64)) ^ aswz));
        __builtin_amdgcn_s_setprio(1);
        #pragma unroll
        for (int mt = 0; mt < 3; ++mt)
            #pragma unroll
            for (int nt = 0; nt < 2; ++nt)
                acc[mt][nt] = __builtin_amdgcn_mfma_f32_16x16x32_f16(a[mt], b[nt], acc[mt][nt], 0, 0, 0);
        __builtin_amdgcn_s_setprio(0);
    };

    auto epi = [&](const float (&bv)[2]) {
        #pragma unroll
        for (int nt = 0; nt < 2; ++nt) {
            int col = wc*32 + nt*16 + l15;
            #pragma unroll
            for (int mt = 0; mt < 3; ++mt)
                #pragma unroll
                for (int i = 0; i < 4; ++i) {
                    int row = mt*16 + lg*4 + i;
                    float v = fmaxf(acc[mt][nt][i] + bv[nt], 0.f);
                    uint off = (uint)(row*PITCHB + col*2) ^ (uint)((row & 7) << 4);
                    *(f16*)((char*)sX + off) = (f16)v;
                }
        }
    };
    // L0 epilogue: += SE/SO, bias, relu
    auto epi0 = [&](const float (&bv)[2]) {
        #pragma unroll
        for (int mt = 0; mt < 3; ++mt)
            #pragma unroll
            for (int i = 0; i < 4; ++i) {
                int row = mt*16 + lg*4 + i;
                int sei = s_sei[row], soi = s_soi[row];
                #pragma unroll
                for (int nt = 0; nt < 2; ++nt) {
                    int col = wc*32 + nt*16 + l15;
                    float addv = (float)se[sei + col] + (float)so[soi + col];
                    float v = fmaxf(acc[mt][nt][i] + addv + bv[nt], 0.f);
                    uint off = (uint)(row*PITCHB + col*2) ^ (uint)((row & 7) << 4);
                    *(f16*)((char*)sX + off) = (f16)v;
                }
            }
    };

    __syncthreads();   // header visible

    // ================= layer 0 : 19 ksteps, X in 3 staged chunks =================
    zacc();
    stageXc(0);
    stageW(sBB[0], wt0, 0);
    stageW(sBB[1], wt0, 1);
    waitv0(); barrier();                        // RACE FIX: drain ALL waves' X loads
    #pragma unroll
    for (int ks = 0; ks < 7; ++ks) {
        stageW(sBB[(ks + 2) % 3], wt0, ks + 2);
        computeK(sBB[ks % 3], ks);
        waitv4(); barrier();
    }
    stageW(sBB[0], wt0, 9);                     // ks7
    computeK(sBB[1], 7);
    waitv4(); barrier();                        // all chunk0 reads done
    stageXc(1);
    waitv0(); barrier();                        // X1 (+W8,W9) landed; re-prime
    #pragma unroll
    for (int ks = 8; ks < 15; ++ks) {
        stageW(sBB[(ks + 2) % 3], wt0, ks + 2);
        computeK(sBB[ks % 3], ks - 8);
        waitv4(); barrier();
    }
    stageW(sBB[2], wt0, 17);                    // ks15
    computeK(sBB[0], 7);
    waitv4(); barrier();                        // all chunk1 reads done
    stageXc2();
    waitv0();                                   // X2 (+W16,W17) landed
    if (tid < 48) {                             // cell + zero fill over dummy region
        uint base = (uint)(tid * 256);
        uint sw   = (uint)((tid & 7) << 4);
        f16x2 cv = { (f16)s_cx[tid], (f16)s_cy[tid] };
        *(f16x2*)((char*)sX + base + (128u ^ sw)) = cv;
        f16x2 z = { (f16)0.f, (f16)0.f };
        #pragma unroll
        for (int q = 66; q < 96; q += 2)
            *(f16x2*)((char*)sX + base + (((uint)(q*2)) ^ sw)) = z;
    }
    waitlgkm(); barrier();
    stageW(sBB[0], wt0, 18);
    computeK2(sBB[1], 0);                       // ks16
    computeK2(sBB[2], 1);                       // ks17
    waitv0();
    computeK2(sBB[0], 2);                       // ks18
    barrier();                                  // all L0 reads done

    // ================= layers 1..3 =================
    const f16* Ws[3] = {wt1, wt2, wt3};
    #pragma unroll
    for (int L = 0; L < 3; ++L) {
        stageW(sBB[0], Ws[L], 0);
        stageW(sBB[1], Ws[L], 1);
        if (L == 0) epi0(bvL[0]); else epi(bvL[L]);
        zacc();
        waitv4(); waitlgkm(); barrier();
        #pragma unroll
        for (int ks = 0; ks < 6; ++ks) {
            stageW(sBB[(ks + 2) % 3], Ws[L], ks + 2);
            computeK(sBB[ks % 3], ks);
            waitv4(); barrier();
        }
        computeK(sBB[0], 6);
        waitv0(); barrier();
        computeK(sBB[1], 7);
        barrier();
    }
    epi(bvL[3]);
    waitlgkm(); barrier();

    // ---- layer 4 : 256 -> 27 (padded 32), wave 0 only, + weighted segment sums ----
    if (wc == 0) {
        f32x4 a4[3][2];
        #pragma unroll
        for (int mt = 0; mt < 3; ++mt)
            #pragma unroll
            for (int nt = 0; nt < 2; ++nt)
                #pragma unroll
                for (int i = 0; i < 4; ++i) a4[mt][nt][i] = 0.f;
        gemmT<8,2,32>(sX, wt4, l15, lg, abase, aswz, a4);
        int split = 36 - (R0 % 36);
        #pragma unroll
        for (int nt = 0; nt < 2; ++nt) {
            int col = nt*16 + l15;
            float s0 = 0.f, s1 = 0.f;
            #pragma unroll
            for (int mt = 0; mt < 3; ++mt)
                #pragma unroll
                for (int i = 0; i < 4; ++i) {
                    int row = mt*16 + lg*4 + i;
                    float v = (a4[mt][nt][i] + bv4[nt]) * s_wgt[row];
                    if (row < split) s0 += v; else s1 += v;
                }
            s0 += __shfl_xor(s0, 16, 64);
            s0 += __shfl_xor(s0, 32, 64);
            s1 += __shfl_xor(s1, 16, 64);
            s1 += __shfl_xor(s1, 32, 64);
            if (lg == 0 && col < 27) {
                __builtin_nontemporal_store(s0, &partial[(size_t)blockIdx.x*56 + col]);
                __builtin_nontemporal_store(s1, &partial[(size_t)blockIdx.x*56 + 28 + col]);
            }
        }
    }
}

// ---------------- kernel 4: combine <=2 window partials per bq ----------------
__global__ __launch_bounds__(256) void k_red(const float* __restrict__ partial,
                                             float* __restrict__ out) {
    int i = blockIdx.x * 256 + threadIdx.x;
    if (i >= NBQ * 27) return;
    int bq = i / 27, col = i - bq*27;
    int r_lo = bq * 36;
    int w0 = r_lo / 48, w1 = (r_lo + 35) / 48;
    float s = 0.f;
    for (int w = w0; w <= w1; ++w) {
        int seg = (bq == (w*48)/36) ? 0 : 1;
        s += __builtin_nontemporal_load(&partial[(size_t)w*56 + seg*28 + col]);
    }
    out[i] = s;
}

// ---------------- launch ----------------
extern "C" void kernel_launch(void* const* d_in, const int* in_sizes, int n_in,
                              void* d_out, int out_size, void* d_ws, size_t ws_size,
                              hipStream_t stream) {
    const float* inp   = (const float*)d_in[0];
    const float* coord = (const float*)d_in[1];
    const float* cellp = (const float*)d_in[2];
    const float* enc_w = (const float*)d_in[3];
    const float* enc_b = (const float*)d_in[4];
    const float* w0 = (const float*)d_in[5];
    const float* b0 = (const float*)d_in[6];
    const float* w1 = (const float*)d_in[7];
    const float* b1 = (const float*)d_in[8];
    const float* w2 = (const float*)d_in[9];
    const float* b2 = (const float*)d_in[10];
    const float* w3 = (const float*)d_in[11];
    const float* b3 = (const float*)d_in[12];
    const float* w4 = (const float*)d_in[13];
    const float* b4 = (const float*)d_in[14];
    float* outp = (float*)d_out;

    float* ws    = (float*)d_ws;
    f16*   feat  = (f16*)ws;                          // FEAT_ELEMS halfs
    float* wgtw  = (float*)(feat + FEAT_ELEMS);       // NROWS
    int*   iposw = (int*)(wgtw + NROWS);
    float* partial = (float*)(iposw + NROWS);         // NWG*56
    f16*   wt0   = (f16*)(partial + (size_t)NWG*56);  // 19*256*32
    f16*   wt1   = wt0 + 19*256*32;
    f16*   wt2   = wt1 + 65536;
    f16*   wt3   = wt2 + 65536;
    f16*   wt4   = wt3 + 65536;                       // 8192
    f16*   w0x   = wt4 + 8192;                        // 9*256*32
    f16*   w0y   = w0x + 9*256*32;
    char*  tbl   = (char*)(w0y + 9*256*32);           // table region start

    size_t fixedBytes = (size_t)(tbl - (char*)d_ws);
    size_t f32Bytes   = (size_t)2 * NSE * 256 * sizeof(float);
    bool   useF32     = (fixedBytes + f32Bytes) <= ws_size;

    k_pre<<<NB_CONV + NB_WCVT + NB_PW, 256, 0, stream>>>(
        inp, enc_w, enc_b, feat,
        w0, w1, w2, w3, w4, wt0, wt1, wt2, wt3, wt4, w0x, w0y,
        coord, wgtw, iposw);

    if (useF32) {
        float* sep = (float*)tbl;
        float* sop = sep + (size_t)NSE*256;
        k_seso<float><<<NSE/48, 256, 0, stream>>>(coord, w0x, w0y, sep, sop);
        k_mlp<float><<<NWG, 512, 0, stream>>>(cellp, feat, wgtw, iposw,
                                              wt0, wt1, wt2, wt3, wt4, sep, sop,
                                              b0, b1, b2, b3, b4, partial);
    } else {
        f16* sep = (f16*)tbl;
        f16* sop = sep + (size_t)NSE*256;
        k_seso<f16><<<NSE/48, 256, 0, stream>>>(coord, w0x, w0y, sep, sop);
        k_mlp<f16><<<NWG, 512, 0, stream>>>(cellp, feat, wgtw, iposw,
                                            wt0, wt1, wt2, wt3, wt4, sep, sop,
                                            b0, b1, b2, b3, b4, partial);
    }
    k_red<<<(NBQ*27 + 255)/256, 256, 0, stream>>>(partial, outp);
}